// Round 7
// baseline (195.237 us; speedup 1.0000x reference)
//
#include <hip/hip_runtime.h>
#include <hip/hip_bf16.h>

typedef _Float16 f16x2 __attribute__((ext_vector_type(2)));
typedef _Float16 f16x4 __attribute__((ext_vector_type(4)));
typedef _Float16 f16x8 __attribute__((ext_vector_type(8)));
typedef float    f32x4 __attribute__((ext_vector_type(4)));
typedef float    f32x16 __attribute__((ext_vector_type(16)));

#define IN_DIM   32
#define EDGE_DIM 16
#define HDIM     64
#define OUT_DIM  6
#define BN_EPS   1e-5f

// ============ zero degI ============
__global__ void k_zero(uint4* __restrict__ p, int n16) {
    int i = blockIdx.x * 256 + threadIdx.x;
    if (i < n16) p[i] = make_uint4(0u, 0u, 0u, 0u);
}

// ============ fused setup: pack We (32x32 B-frags) | encode h0 | prep eaH+deg | bounds ============
// WeB layout: [layer][h][oh][lane<64] f16x8 (16B).  lane: col = oh*32+(lane&31),
// k = 8*(lane>>5)+j  ->  We[layer][k][h*64+col]
__global__ __launch_bounds__(256) void k_setup(
    const float* __restrict__ We, uint4* __restrict__ WeB,
    const float* __restrict__ x, const float* __restrict__ Wx,
    const float* __restrict__ bx, float* __restrict__ h,
    const float* __restrict__ ea, _Float16* __restrict__ eaH,
    const int* __restrict__ dstI, int* __restrict__ degI,
    const int* __restrict__ batch, int* __restrict__ start,
    int N, int E, int G, int PACKB, int ENCB, int PREPB)
{
    int bid = blockIdx.x;
    int t = threadIdx.x;

    if (bid < PACKB) {                       // ---- pack: 3*64*2 tiles x 64 lanes = 24576 threads
        int tid = bid * 256 + t;
        int tile = tid >> 6, lane = tid & 63;
        int layer = tile >> 7;
        int r = tile & 127;                  // h*2 + oh
        int hh = r >> 1, oh = r & 1;
        int col = hh * 64 + oh * 32 + (lane & 31);
        int kbase = 8 * (lane >> 5);
        const float* base = We + (size_t)layer * 65536 + col;
        f16x8 v;
        #pragma unroll
        for (int j = 0; j < 8; ++j) v[j] = (_Float16)base[(size_t)(kbase + j) * 4096];
        WeB[(size_t)tile * 64 + lane] = __builtin_bit_cast(uint4, v);
        return;
    }
    bid -= PACKB;
    if (bid < ENCB) {                        // ---- encode: h0 = x @ Wx + bx
        int tid = bid * 256 + t;
        int n = tid >> 4, jq = tid & 15;
        if (n >= N) return;
        const float4* W4 = (const float4*)Wx;
        float4 acc = ((const float4*)bx)[jq];
        const float4* xv = (const float4*)(x + (size_t)n * IN_DIM);
        #pragma unroll
        for (int k4 = 0; k4 < 8; ++k4) {
            float4 xk = xv[k4];
            #pragma unroll
            for (int i = 0; i < 4; ++i) {
                float xs = (i == 0) ? xk.x : (i == 1) ? xk.y : (i == 2) ? xk.z : xk.w;
                float4 ww = W4[(k4 * 4 + i) * 16 + jq];
                acc.x += xs * ww.x; acc.y += xs * ww.y; acc.z += xs * ww.z; acc.w += xs * ww.w;
            }
        }
        ((float4*)h)[tid] = acc;
        return;
    }
    bid -= ENCB;
    if (bid < PREPB) {                       // ---- prep: eaH f16 convert + degree count
        int tid = bid * 256 + t;
        int E8 = E * 8;
        if (tid < E8) {
            float2 v = ((const float2*)ea)[tid];
            f16x2 r; r[0] = (_Float16)v.x; r[1] = (_Float16)v.y;
            ((f16x2*)eaH)[tid] = r;
        }
        if (tid < E) atomicAdd(&degI[dstI[tid]], 1);
        return;
    }
    // ---- bounds: start[g] via binary search (batch sorted)
    if (t <= G) {
        int lo = 0, hi = N;
        while (lo < hi) { int mid = (lo + hi) >> 1; if (batch[mid] < t) lo = mid + 1; else hi = mid; }
        start[t] = lo;
    }
}

// ============ CSR build: parallel 3-stage scan, then place ============
__global__ void k_scan_local(const int* __restrict__ degI, int* __restrict__ rowptr,
                             int* __restrict__ partials, int N) {
    __shared__ int buf[256];
    int b = blockIdx.x, t = threadIdx.x;
    int i = b * 256 + t;
    int v = (i < N) ? degI[i] : 0;
    buf[t] = v;
    __syncthreads();
    #pragma unroll
    for (int ofs = 1; ofs < 256; ofs <<= 1) {
        int xv = (t >= ofs) ? buf[t - ofs] : 0;
        __syncthreads();
        buf[t] += xv;
        __syncthreads();
    }
    if (i < N) rowptr[i] = buf[t] - v;
    if (t == 255) partials[b] = buf[255];
}

__global__ void k_scan_top(int* __restrict__ partials, int nb) {
    __shared__ int buf[256];
    int t = threadIdx.x;
    int v = (t < nb) ? partials[t] : 0;
    buf[t] = v;
    __syncthreads();
    #pragma unroll
    for (int ofs = 1; ofs < 256; ofs <<= 1) {
        int xv = (t >= ofs) ? buf[t - ofs] : 0;
        __syncthreads();
        buf[t] += xv;
        __syncthreads();
    }
    if (t < nb) partials[t] = buf[t] - v;
    if (t == 0) partials[nb] = buf[255];
}

__global__ void k_scan_add(int* __restrict__ rowptr, int* __restrict__ cursor,
                           const int* __restrict__ partials, int N, int nb) {
    int i = blockIdx.x * 256 + threadIdx.x;
    if (i < N) {
        int r = rowptr[i] + partials[blockIdx.x];
        rowptr[i] = r;
        cursor[i] = r;
    }
    if (i == 0) rowptr[N] = partials[nb];
}

__global__ void k_place(const int* __restrict__ dstI, int* __restrict__ cursor,
                        int* __restrict__ eidx, int E) {
    int e = blockIdx.x * 256 + threadIdx.x;
    if (e < E) {
        int p = atomicAdd(&cursor[dstI[e]], 1);
        eidx[p] = e;
    }
}

// ============ fused edge MLP (32x32x16 MFMA, K=16 exact) + weighted h-reduce ============
// Block: (64-edge group) x (h-half). 4 waves = (edge-half gp) x (o-half oh).
// Per wave: 32 edges x 32 outs, 32 h iters, 1 MFMA/iter. Stores f16 msg partials.
__global__ __launch_bounds__(256, 6) void k_edge(
    const uint4* __restrict__ eaH4,     // [E][2] uint4 (16 f16)
    const uint4* __restrict__ WeB,      // layer base: [64h][2oh][64lane] uint4
    const float* __restrict__ be,       // layer base: [4096] = [h*64+o]
    const float* __restrict__ hin,      // [N][64]
    const int* __restrict__ srcI,
    _Float16* __restrict__ msgP,        // [2][E][64] f16
    int E)
{
    __shared__ float hsT[32][68];       // [h_local][edge_local]
    __shared__ float beL[2048];
    const int t = threadIdx.x;
    const int l = t & 63;
    const int w = t >> 6;
    const int eg = blockIdx.x >> 1;
    const int hhalf = blockIdx.x & 1;
    const int eb = eg * 64;
    const int hbase = hhalf * 32;

    // ---- stage hsT: wave w stages h-rows w*8..w*8+7 for all 64 edges ----
    {
        int egc = min(eb + l, E - 1);
        int s = srcI[egc];
        const float4* hp = (const float4*)(hin + (size_t)s * HDIM + hbase + w * 8);
        float4 a = hp[0], b = hp[1];
        hsT[w*8+0][l] = a.x; hsT[w*8+1][l] = a.y; hsT[w*8+2][l] = a.z; hsT[w*8+3][l] = a.w;
        hsT[w*8+4][l] = b.x; hsT[w*8+5][l] = b.y; hsT[w*8+6][l] = b.z; hsT[w*8+7][l] = b.w;
    }
    // ---- stage beL: this h-half's 2048 biases ----
    {
        const float4* bg = (const float4*)(be + hbase * 64);
        float4* bs = (float4*)beL;
        bs[t] = bg[t];
        bs[256 + t] = bg[256 + t];
    }
    __syncthreads();

    const int gp  = w >> 1;
    const int oh  = w & 1;
    const int ebw = eb + gp * 32;
    const int elw = gp * 32;
    const int row = l & 31;
    const int kg  = l >> 5;              // k-group (8 k each)
    const int obase = oh * 32;

    // ---- A fragment: 32 edges x K=16 (exact, no padding) ----
    int ea_e = min(ebw + row, E - 1);
    f16x8 A = __builtin_bit_cast(f16x8, eaH4[(size_t)ea_e * 2 + kg]);

    // ---- msg accumulators: reg j -> edge row (j&3)+8*(j>>2)+4*kg, col obase+(l&31) ----
    float m[16];
    #pragma unroll
    for (int j = 0; j < 16; ++j) m[j] = 0.f;

    const uint4* Bb = WeB + (size_t)(hbase * 2 + oh) * 64 + l;
    uint4 Bv = Bb[0];

    for (int hh = 0; hh < 32; ++hh) {
        uint4 Bn;
        if (hh < 31) Bn = Bb[(size_t)(hh + 1) * 128];
        float bias = beL[hh * 64 + obase + (l & 31)];
        f32x16 cin;
        #pragma unroll
        for (int j = 0; j < 16; ++j) cin[j] = bias;
        f32x16 z = __builtin_amdgcn_mfma_f32_32x32x16_f16(
            A, __builtin_bit_cast(f16x8, Bv), cin, 0, 0, 0);
        float4 q0 = *(const float4*)&hsT[hh][elw + 4 * kg + 0];
        float4 q1 = *(const float4*)&hsT[hh][elw + 4 * kg + 8];
        float4 q2 = *(const float4*)&hsT[hh][elw + 4 * kg + 16];
        float4 q3 = *(const float4*)&hsT[hh][elw + 4 * kg + 24];
        m[0]  += fmaxf(z[0],  0.f) * q0.x;
        m[1]  += fmaxf(z[1],  0.f) * q0.y;
        m[2]  += fmaxf(z[2],  0.f) * q0.z;
        m[3]  += fmaxf(z[3],  0.f) * q0.w;
        m[4]  += fmaxf(z[4],  0.f) * q1.x;
        m[5]  += fmaxf(z[5],  0.f) * q1.y;
        m[6]  += fmaxf(z[6],  0.f) * q1.z;
        m[7]  += fmaxf(z[7],  0.f) * q1.w;
        m[8]  += fmaxf(z[8],  0.f) * q2.x;
        m[9]  += fmaxf(z[9],  0.f) * q2.y;
        m[10] += fmaxf(z[10], 0.f) * q2.z;
        m[11] += fmaxf(z[11], 0.f) * q2.w;
        m[12] += fmaxf(z[12], 0.f) * q3.x;
        m[13] += fmaxf(z[13], 0.f) * q3.y;
        m[14] += fmaxf(z[14], 0.f) * q3.z;
        m[15] += fmaxf(z[15], 0.f) * q3.w;
        Bv = Bn;
    }

    // ---- store f16 msg partials: coalesced 2B x 32-lane segments ----
    _Float16* mw = msgP + (size_t)hhalf * E * 64 + obase + (l & 31);
    #pragma unroll
    for (int j = 0; j < 16; ++j) {
        int e = ebw + (j & 3) + 8 * (j >> 2) + 4 * kg;
        if (e < E) mw[(size_t)e * 64] = (_Float16)m[j];
    }
}

// ============ node update: CSR gather-mean (f16 msg), root GEMV, relu, BN, residual ============
__global__ void k_update(
    const _Float16* __restrict__ msgP, const int* __restrict__ rowptr,
    const int* __restrict__ eidx,
    const float* __restrict__ hin, const float* __restrict__ Wroot,
    const float* __restrict__ broot, const float* __restrict__ gam,
    const float* __restrict__ bet, const float* __restrict__ rmean,
    const float* __restrict__ rvar, float* __restrict__ hout, int N, int E)
{
    int tid = blockIdx.x * 256 + threadIdx.x;   // N*16
    int n = tid >> 4, jq = tid & 15;
    if (n >= N) return;
    int r0 = rowptr[n], r1 = rowptr[n + 1];
    float4 s = make_float4(0.f, 0.f, 0.f, 0.f);
    const f16x4* m4 = (const f16x4*)msgP;
    for (int i = r0; i < r1; ++i) {
        int eid = eidx[i];
        f16x4 a = m4[(size_t)eid * 16 + jq];
        f16x4 b = m4[((size_t)E + eid) * 16 + jq];
        s.x += (float)a[0] + (float)b[0];
        s.y += (float)a[1] + (float)b[1];
        s.z += (float)a[2] + (float)b[2];
        s.w += (float)a[3] + (float)b[3];
    }
    float dinv = 1.0f / fmaxf((float)(r1 - r0), 1.0f);
    float4 acc = ((const float4*)broot)[jq];
    acc.x += s.x * dinv; acc.y += s.y * dinv; acc.z += s.z * dinv; acc.w += s.w * dinv;
    const float4* W4 = (const float4*)Wroot;
    const float4* hv = (const float4*)(hin + (size_t)n * HDIM);
    #pragma unroll
    for (int k4 = 0; k4 < 16; ++k4) {
        float4 hk = hv[k4];
        #pragma unroll
        for (int i = 0; i < 4; ++i) {
            float hsc = (i == 0) ? hk.x : (i == 1) ? hk.y : (i == 2) ? hk.z : hk.w;
            float4 ww = W4[(k4 * 4 + i) * 16 + jq];
            acc.x += hsc * ww.x; acc.y += hsc * ww.y; acc.z += hsc * ww.z; acc.w += hsc * ww.w;
        }
    }
    acc.x = fmaxf(acc.x, 0.f); acc.y = fmaxf(acc.y, 0.f);
    acc.z = fmaxf(acc.z, 0.f); acc.w = fmaxf(acc.w, 0.f);
    float4 g4 = ((const float4*)gam)[jq];
    float4 b4 = ((const float4*)bet)[jq];
    float4 mm4 = ((const float4*)rmean)[jq];
    float4 v4 = ((const float4*)rvar)[jq];
    float4 hres = ((const float4*)hin)[tid];
    float4 y;
    y.x = g4.x * (acc.x - mm4.x) * rsqrtf(v4.x + BN_EPS) + b4.x + hres.x;
    y.y = g4.y * (acc.y - mm4.y) * rsqrtf(v4.y + BN_EPS) + b4.y + hres.y;
    y.z = g4.z * (acc.z - mm4.z) * rsqrtf(v4.z + BN_EPS) + b4.z + hres.z;
    y.w = g4.w * (acc.w - mm4.w) * rsqrtf(v4.w + BN_EPS) + b4.w + hres.w;
    ((float4*)hout)[tid] = y;
}

// ============ fused pool (segment mean) + MLP head; no atomics ============
__global__ __launch_bounds__(256) void k_pool_head(
    const float* __restrict__ h, const int* __restrict__ start,
    const float* __restrict__ W1, const float* __restrict__ b1,
    const float* __restrict__ W2, const float* __restrict__ b2,
    float* __restrict__ out)
{
    __shared__ float sums[16][68];
    __shared__ float pl[HDIM];
    __shared__ float zl[HDIM];
    int g = blockIdx.x;
    int s0 = start[g], s1 = start[g + 1];
    int t = threadIdx.x, jq = t & 15, rp = t >> 4;
    float4 acc = make_float4(0.f, 0.f, 0.f, 0.f);
    for (int n = s0 + rp; n < s1; n += 16) {
        float4 v = ((const float4*)h)[(size_t)n * 16 + jq];
        acc.x += v.x; acc.y += v.y; acc.z += v.z; acc.w += v.w;
    }
    *(float4*)&sums[rp][jq * 4] = acc;
    __syncthreads();
    if (t < HDIM) {
        float a = 0.f;
        #pragma unroll
        for (int r = 0; r < 16; ++r) a += sums[r][t];
        float cnt = (float)(s1 - s0);
        pl[t] = a / fmaxf(cnt, 1.0f);
    }
    __syncthreads();
    if (t < HDIM) {
        float a = b1[t];
        #pragma unroll
        for (int k = 0; k < HDIM; ++k) a += pl[k] * W1[k * HDIM + t];
        zl[t] = fmaxf(a, 0.f);
    }
    __syncthreads();
    if (t < OUT_DIM) {
        float a = b2[t];
        #pragma unroll
        for (int k = 0; k < HDIM; ++k) a += zl[k] * W2[k * OUT_DIM + t];
        out[(size_t)g * OUT_DIM + t] = a;
    }
}

// ============ launch ============
extern "C" void kernel_launch(void* const* d_in, const int* in_sizes, int n_in,
                              void* d_out, int out_size, void* d_ws, size_t ws_size,
                              hipStream_t stream) {
    const float* x     = (const float*)d_in[0];
    const float* eattr = (const float*)d_in[1];
    const int*   src   = (const int*)d_in[2];
    const int*   dst   = (const int*)d_in[3];
    const int*   batch = (const int*)d_in[4];
    const float* Wx    = (const float*)d_in[5];
    const float* bx    = (const float*)d_in[6];
    const float* We    = (const float*)d_in[7];
    const float* be    = (const float*)d_in[8];
    const float* Wroot = (const float*)d_in[9];
    const float* broot = (const float*)d_in[10];
    const float* gam   = (const float*)d_in[11];
    const float* bet   = (const float*)d_in[12];
    const float* rmean = (const float*)d_in[13];
    const float* rvar  = (const float*)d_in[14];
    const float* W1    = (const float*)d_in[15];
    const float* b1    = (const float*)d_in[16];
    const float* W2    = (const float*)d_in[17];
    const float* b2    = (const float*)d_in[18];
    float* out = (float*)d_out;

    const int N = in_sizes[0] / IN_DIM;
    const int E = in_sizes[2];
    const int G = out_size / OUT_DIM;

    char* ws = (char*)d_ws;
    size_t off = 0;
    auto alloc = [&](size_t bytes) -> void* {
        void* p = ws + off;
        off = (off + bytes + 255) & ~(size_t)255;
        return p;
    };
    float*    h0      = (float*)alloc((size_t)N * HDIM * 4);
    float*    h1      = (float*)alloc((size_t)N * HDIM * 4);
    _Float16* eaH     = (_Float16*)alloc((size_t)E * 16 * 2);
    uint4*    WeB     = (uint4*)alloc((size_t)3 * 128 * 64 * 16);   // [3][64][2][64] x 16B
    int*      start   = (int*)alloc((size_t)(G + 1) * 4);
    int*      rowptr  = (int*)alloc((size_t)(N + 1) * 4);
    int*      cursor  = (int*)alloc((size_t)N * 4);
    int*      eidx    = (int*)alloc((size_t)E * 4);
    _Float16* msgP    = (_Float16*)alloc((size_t)2 * E * HDIM * 2); // f16
    int*      degI    = (int*)alloc((size_t)((N + 3) & ~3) * 4);
    const int nb      = (N + 255) / 256;
    int*      partials= (int*)alloc((size_t)(nb + 1) * 4);
    (void)ws_size; (void)n_in;

    const int n16 = ((N + 3) & ~3) / 4;
    k_zero<<<(n16 + 255) / 256, 256, 0, stream>>>((uint4*)degI, n16);

    const int PACKB = 96;                       // 3*128 tiles * 64 lanes / 256
    const int ENCB  = (N * 16 + 255) / 256;
    const int PREPB = (E * 8 + 255) / 256;
    k_setup<<<PACKB + ENCB + PREPB + 1, 256, 0, stream>>>(
        We, WeB, x, Wx, bx, h0, eattr, eaH, dst, degI, batch, start,
        N, E, G, PACKB, ENCB, PREPB);
    k_scan_local<<<nb, 256, 0, stream>>>(degI, rowptr, partials, N);
    k_scan_top<<<1, 256, 0, stream>>>(partials, nb);
    k_scan_add<<<nb, 256, 0, stream>>>(rowptr, cursor, partials, N, nb);
    k_place<<<(E + 255) / 256, 256, 0, stream>>>(dst, cursor, eidx, E);

    const float* hin = h0;
    float* hout = h1;
    const int edgeBlocks = ((E + 63) / 64) * 2;
    for (int l = 0; l < 3; ++l) {
        k_edge<<<edgeBlocks, 256, 0, stream>>>(
            (const uint4*)eaH, WeB + (size_t)l * 8192, be + (size_t)l * 4096,
            hin, src, msgP, E);
        k_update<<<(N * 16 + 255) / 256, 256, 0, stream>>>(
            msgP, rowptr, eidx, hin, Wroot + (size_t)l * 4096, broot + (size_t)l * 64,
            gam + (size_t)l * 64, bet + (size_t)l * 64, rmean + (size_t)l * 64,
            rvar + (size_t)l * 64, hout, N, E);
        float* tmp = hout; hout = (float*)hin; hin = tmp;
    }
    k_pool_head<<<G, 256, 0, stream>>>(hin, start, W1, b1, W2, b2, out);
}